// Round 11
// baseline (186.983 us; speedup 1.0000x reference)
//
#include <hip/hip_runtime.h>

#define BK 32          // fp32 k-elements per stage (128 B per row-visit)
#define LROW 40        // ushorts per LDS row: 32 bf16 + 8 pad (80 B, 16B-aligned)
#define NCHUNK 256     // K-chunks; KC = D/NCHUNK = 1024
#define THREADS 1024

typedef float f32x4 __attribute__((ext_vector_type(4)));
typedef short s16x8 __attribute__((ext_vector_type(8)));

// HW packed fp32->bf16 RTNE (2 elems / instr); no builtin on gfx950 -> asm.
__device__ __forceinline__ unsigned cvtpk(float lo, float hi) {
  unsigned r;
  asm("v_cvt_pk_bf16_f32 %0, %1, %2" : "=v"(r) : "v"(lo), "v"(hi));
  return r;
}

__global__ void __launch_bounds__(64) zero_kernel(float* out) {
  if (threadIdx.x == 0) out[0] = 0.f;
}

// Non-draining barrier: lgkmcnt(0) + s_barrier + sched pin. Global loads
// stay in flight across it.
__device__ __forceinline__ void barrier_nodrain() {
  asm volatile("s_waitcnt lgkmcnt(0)" ::: "memory");
  __builtin_amdgcn_s_barrier();
  __builtin_amdgcn_sched_barrier(0);
}

// Split-K GEMM: block b owns K-chunk [b*KC,(b+1)*KC), full 256x256 partial
// into ws + b*65536 (fp16). 16 waves (4x4), wave tile 64x64, acc=64 regs.
// bf16 LDS ring-2 [buf][mat][256][40] = 80 KiB.
// QUEUE DISCIPLINE (the R11 experiment): single reg buffer s[q]; per-q fused
// {consume s[q] (vmcnt(3) by FIFO: 3 younger loads outstanding) -> ds_write;
//  reload s[q] for stage t+2} pinned by sched_barrier(0). The per-wave VMEM
// queue NEVER drains below 3 (R1/R9's sawtooth drained to 0 every stage;
// R8 showed never-empty queue = ~HBM-floor line service).
__global__ void __launch_bounds__(THREADS, 4)
gemm_kernel(const float* __restrict__ V1, const float* __restrict__ V2,
            _Float16* __restrict__ ws, int D, int KC) {
  __shared__ __align__(16) unsigned short lds[2 * 2 * 256 * LROW];  // 80 KiB

  const int tid  = threadIdx.x;
  const int lane = tid & 63;
  const int wid  = tid >> 6;    // 0..15
  const int wm   = wid >> 2;    // 0..3 (M)
  const int wn   = wid & 3;     // 0..3 (N)
  const int lr   = lane & 15;
  const int lg   = lane >> 4;
  const int ns   = KC / BK;     // 32

  // staging: 4 row-visits/thread (8 lanes x 16 B cover one 128 B row-window)
  const int c8    = tid & 7;
  const int rbase = tid >> 3;   // 0..127
  const float* gp[4];
  int ob[4];
#pragma unroll
  for (int v = 0; v < 4; ++v) {
    const int idx = rbase + 128 * v;   // 0..511
    const int mat = idx >> 8;
    const int row = idx & 255;
    gp[v] = (mat ? V2 : V1)
        + (size_t)row * (size_t)D
        + (size_t)blockIdx.x * (size_t)KC + (size_t)c8 * 4;
    ob[v] = (mat * 256 + row) * LROW + c8 * 4;   // ushort units
  }

  f32x4 acc[4][4];
#pragma unroll
  for (int a = 0; a < 4; ++a)
#pragma unroll
    for (int b = 0; b < 4; ++b) acc[a][b] = f32x4{0.f, 0.f, 0.f, 0.f};

  float4 s[4];

  // consume s[q] into LDS buf, then immediately reload s[q] with next data.
  auto wr_issue = [&](int buf, int q, bool reload) {
    uint2 w;
    w.x = cvtpk(s[q].x, s[q].y);
    w.y = cvtpk(s[q].z, s[q].w);
    *(uint2*)&lds[buf * (2 * 256 * LROW) + ob[q]] = w;
    if (reload) {
      s[q] = *(const float4*)gp[q];
      gp[q] += BK;
    }
    __builtin_amdgcn_sched_barrier(0);
  };

  // prologue: load stage0 -> regs -> LDS buf0; load stage1 -> regs
#pragma unroll
  for (int q = 0; q < 4; ++q) { s[q] = *(const float4*)gp[q]; gp[q] += BK; }
#pragma unroll
  for (int q = 0; q < 4; ++q) wr_issue(0, q, true);   // write st0, load st1
  barrier_nodrain();

  for (int t = 0; t < ns; ++t) {
    const int buf = t & 1;

    s16x8 bf[4];
#pragma unroll
    for (int nf = 0; nf < 4; ++nf) {
      int r = wn * 64 + nf * 16 + lr;
      bf[nf] = *(const s16x8*)&lds[((buf * 2 + 1) * 256 + r) * LROW + lg * 8];
    }
#pragma unroll
    for (int mf = 0; mf < 4; ++mf) {
      int r = wm * 64 + mf * 16 + lr;
      s16x8 af = *(const s16x8*)&lds[((buf * 2 + 0) * 256 + r) * LROW + lg * 8];
#pragma unroll
      for (int nf = 0; nf < 4; ++nf)
        acc[mf][nf] = __builtin_amdgcn_mfma_f32_16x16x32_bf16(af, bf[nf], acc[mf][nf], 0, 0, 0);
    }

    if (t + 2 < ns) {
#pragma unroll
      for (int q = 0; q < 4; ++q) wr_issue(buf ^ 1, q, true);
    } else if (t + 1 < ns) {
#pragma unroll
      for (int q = 0; q < 4; ++q) wr_issue(buf ^ 1, q, false);  // last write
    }
    barrier_nodrain();
  }

  // C/D layout: col = lane&15, row = (lane>>4)*4 + reg. fp16 partials
  // (|partial| <~ 6*sqrt(1024) ~ 200 << 65504; zmean err ~1e-6, R5-R10 proven).
  _Float16* Cp = ws + (size_t)blockIdx.x * (256 * 256);
#pragma unroll
  for (int mf = 0; mf < 4; ++mf) {
    int i0 = wm * 64 + mf * 16 + lg * 4;
#pragma unroll
    for (int nf = 0; nf < 4; ++nf) {
      int j = wn * 64 + nf * 16 + lr;
#pragma unroll
      for (int v = 0; v < 4; ++v)
        Cp[(size_t)(i0 + v) * 256 + j] = (_Float16)acc[mf][nf][v];
    }
  }
}

// Sum P fp16 partials, z = dot/D, BCE vs identity labels:
//   diag: softplus(z) - z ; off-diag: softplus(z)
__global__ void __launch_bounds__(256)
loss_kernel(const _Float16* __restrict__ ws, float* __restrict__ out, int P, float invD) {
  const int i = blockIdx.x, j = threadIdx.x;
  const _Float16* base = ws + i * 256 + j;
  float s = 0.f;
#pragma unroll 8
  for (int p = 0; p < P; ++p) s += (float)base[(size_t)p * 65536];
  float z = s * invD;
  float term = log1pf(expf(z)) - (i == j ? z : 0.f);

  __shared__ float red[256];
  red[j] = term;
  __syncthreads();
  for (int st = 128; st > 0; st >>= 1) {
    if (j < st) red[j] += red[j + st];
    __syncthreads();
  }
  if (j == 0) atomicAdd(out, red[0] * (1.f / 65536.f));
}

extern "C" void kernel_launch(void* const* d_in, const int* in_sizes, int n_in,
                              void* d_out, int out_size, void* d_ws, size_t ws_size,
                              hipStream_t stream) {
  const float* V1 = (const float*)d_in[0];
  const float* V2 = (const float*)d_in[1];
  float* out = (float*)d_out;
  _Float16* ws = (_Float16*)d_ws;

  const int N = 256;
  const int D = in_sizes[0] / N;   // 262144

  int P = NCHUNK;                  // 256 fp16 partials = 32 MB
  while (P > 1 && (size_t)P * 65536 * sizeof(_Float16) > ws_size) P >>= 1;
  const int KC = D / P;            // 1024

  zero_kernel<<<1, 64, 0, stream>>>(out);
  gemm_kernel<<<P, THREADS, 0, stream>>>(V1, V2, ws, D, KC);
  loss_kernel<<<N, 256, 0, stream>>>(ws, out, P, 1.0f / (float)D);
}

// Round 12
// 149.040 us; speedup vs baseline: 1.2546x; 1.2546x over previous
//
#include <hip/hip_runtime.h>

#define BK 32          // fp32 k-elements per pipeline stage (128 B per row-visit)
#define NCHUNK 256     // grid = K-chunks; KC = D/NCHUNK = 1024
#define THREADS 1024

typedef float f32x4 __attribute__((ext_vector_type(4)));
typedef short s16x8 __attribute__((ext_vector_type(8)));

__device__ __forceinline__ unsigned short f2bf(float f) {
  union { float f; unsigned u; } v; v.f = f;
  return (unsigned short)((v.u + 0x7FFFu + ((v.u >> 16) & 1u)) >> 16);  // RTNE
}

__device__ __forceinline__ s16x8 cvt8(f32x4 a, f32x4 b) {
  s16x8 r;
  r[0]=(short)f2bf(a[0]); r[1]=(short)f2bf(a[1]); r[2]=(short)f2bf(a[2]); r[3]=(short)f2bf(a[3]);
  r[4]=(short)f2bf(b[0]); r[5]=(short)f2bf(b[1]); r[6]=(short)f2bf(b[2]); r[7]=(short)f2bf(b[3]);
  return r;
}

__global__ void __launch_bounds__(64) zero_kernel(float* out) {
  if (threadIdx.x == 0) out[0] = 0.f;
}

// R12 = R7 (best e2e, 155.7 us) + per-block k-phase rotation.
// Split-K GEMM: block b owns K-chunk [b*KC,(b+1)*KC), full 256x256 partial
// into ws + b*65536 (fp16). 1024 threads = 16 waves (4x4), wave tile 64x64.
// fp32 LDS ring-2 x 64 KiB, global_load_lds DMA, counted vmcnt(4) (queue
// never empties). NEW: stage t reads k-window ((t + blockIdx) mod ns)*BK —
// k-order within a chunk is commutative for the accumulation, but the
// rotation decorrelates address bits [7:12) across blocks chip-wide,
// spreading concurrent requests over all DRAM channel-selector values
// (anti channel-camping: without it, a stage's 64 KiB differs only in
// bits >=20 -> one channel per block-stage).
__global__ void __launch_bounds__(THREADS, 4)
gemm_kernel(const float* __restrict__ V1, const float* __restrict__ V2,
            _Float16* __restrict__ ws, int D, int KC) {
  __shared__ __align__(16) float lds[2 * 2 * 256 * BK];  // 128 KiB

  const int tid  = threadIdx.x;
  const int lane = tid & 63;
  const int wid  = tid >> 6;    // 0..15
  const int wm   = wid >> 2;    // 0..3 (M)
  const int wn   = wid & 3;     // 0..3 (N)
  const int lr   = lane & 15;
  const int lg   = lane >> 4;
  const int ns   = KC / BK;     // 32 (power of 2)
  const int nsm  = ns - 1;
  const int s0   = blockIdx.x & nsm;   // per-block k-phase rotation

  // loader role: wave covers a 32-row panel of one matrix; 4 instrs x 8 rows.
  const int mat   = wid >> 3;         // 0: V1, 1: V2
  const int panel = (wid & 7) * 32;
  const int lrow8 = lane >> 3;        // row within an 8-row group
  const int lseg  = lane & 7;         // 16B segment
  const int swz   = (lseg * 4) ^ (lrow8 << 2);   // pre-swizzled source offset

  const float* srcM = mat ? V2 : V1;
  const size_t chunk = (size_t)blockIdx.x * (size_t)KC;
  const float* gsrc[4];
#pragma unroll
  for (int i = 0; i < 4; ++i)
    gsrc[i] = srcM + (size_t)(panel + i * 8 + lrow8) * (size_t)D + chunk + swz;

  auto issue = [&](int t, int s) {
    const int tr = (t + s0) & nsm;     // rotated k-window
#pragma unroll
    for (int i = 0; i < 4; ++i) {
      const float* g = gsrc[i] + (size_t)tr * BK;
      float* l = &lds[(((s * 2 + mat) * 256) + panel + i * 8) * BK];  // wave-uniform
      __builtin_amdgcn_global_load_lds(
          (const __attribute__((address_space(1))) void*)g,
          (__attribute__((address_space(3))) void*)l, 16, 0, 0);
    }
  };

  f32x4 acc[4][4];
#pragma unroll
  for (int a = 0; a < 4; ++a)
#pragma unroll
    for (int b = 0; b < 4; ++b) acc[a][b] = f32x4{0.f, 0.f, 0.f, 0.f};

  issue(0, 0);
  issue(1, 1);     // ns >= 2 always

  for (int t = 0; t < ns; ++t) {
    const int s = t & 1;

    // stage t complete: my 4 oldest loads done (4 newer stay in flight).
    if (t + 1 < ns) asm volatile("s_waitcnt vmcnt(4)" ::: "memory");
    else            asm volatile("s_waitcnt vmcnt(0)" ::: "memory");
    __builtin_amdgcn_s_barrier();
    __builtin_amdgcn_sched_barrier(0);

    // B fragments (4x): swizzled f32x4 pair, cvt to bf16
    s16x8 bf[4];
#pragma unroll
    for (int nf = 0; nf < 4; ++nf) {
      int r = wn * 64 + nf * 16 + lr;
      int base = ((s * 2 + 1) * 256 + r) * BK;
      int x = ((r & 7) << 2);
      f32x4 lo = *(const f32x4*)&lds[base + ((lg * 8 + 0) ^ x)];
      f32x4 hi = *(const f32x4*)&lds[base + ((lg * 8 + 4) ^ x)];
      bf[nf] = cvt8(lo, hi);
    }
    // A fragments streamed; MFMA overlaps next frag's ds_read
#pragma unroll
    for (int mf = 0; mf < 4; ++mf) {
      int r = wm * 64 + mf * 16 + lr;
      int base = ((s * 2 + 0) * 256 + r) * BK;
      int x = ((r & 7) << 2);
      f32x4 lo = *(const f32x4*)&lds[base + ((lg * 8 + 0) ^ x)];
      f32x4 hi = *(const f32x4*)&lds[base + ((lg * 8 + 4) ^ x)];
      s16x8 af = cvt8(lo, hi);
#pragma unroll
      for (int nf = 0; nf < 4; ++nf)
        acc[mf][nf] = __builtin_amdgcn_mfma_f32_16x16x32_bf16(af, bf[nf], acc[mf][nf], 0, 0, 0);
    }

    // all waves done READING stage s -> safe to overwrite with stage t+2
    asm volatile("s_waitcnt lgkmcnt(0)" ::: "memory");
    __builtin_amdgcn_s_barrier();
    __builtin_amdgcn_sched_barrier(0);
    if (t + 2 < ns) issue(t + 2, s);
  }

  // C/D layout: col = lane&15, row = (lane>>4)*4 + reg. fp16 partials
  // (|partial| <~ 6*sqrt(1024) ~ 200 << 65504; zmean err ~1e-6 — R5-R11 proven).
  _Float16* Cp = ws + (size_t)blockIdx.x * (256 * 256);
#pragma unroll
  for (int mf = 0; mf < 4; ++mf) {
    int i0 = wm * 64 + mf * 16 + lg * 4;
#pragma unroll
    for (int nf = 0; nf < 4; ++nf) {
      int j = wn * 64 + nf * 16 + lr;
#pragma unroll
      for (int v = 0; v < 4; ++v)
        Cp[(size_t)(i0 + v) * 256 + j] = (_Float16)acc[mf][nf][v];
    }
  }
}

// Sum P fp16 partials, z = dot/D, BCE vs identity labels:
//   diag: softplus(z) - z ; off-diag: softplus(z)
__global__ void __launch_bounds__(256)
loss_kernel(const _Float16* __restrict__ ws, float* __restrict__ out, int P, float invD) {
  const int i = blockIdx.x, j = threadIdx.x;
  const _Float16* base = ws + i * 256 + j;
  float s = 0.f;
#pragma unroll 8
  for (int p = 0; p < P; ++p) s += (float)base[(size_t)p * 65536];
  float z = s * invD;
  float term = log1pf(expf(z)) - (i == j ? z : 0.f);

  __shared__ float red[256];
  red[j] = term;
  __syncthreads();
  for (int st = 128; st > 0; st >>= 1) {
    if (j < st) red[j] += red[j + st];
    __syncthreads();
  }
  if (j == 0) atomicAdd(out, red[0] * (1.f / 65536.f));
}

extern "C" void kernel_launch(void* const* d_in, const int* in_sizes, int n_in,
                              void* d_out, int out_size, void* d_ws, size_t ws_size,
                              hipStream_t stream) {
  const float* V1 = (const float*)d_in[0];
  const float* V2 = (const float*)d_in[1];
  float* out = (float*)d_out;
  _Float16* ws = (_Float16*)d_ws;

  const int N = 256;
  const int D = in_sizes[0] / N;   // 262144

  int P = NCHUNK;                  // 256 fp16 partials = 32 MB
  while (P > 1 && (size_t)P * 65536 * sizeof(_Float16) > ws_size) P >>= 1;
  const int KC = D / P;            // 1024

  zero_kernel<<<1, 64, 0, stream>>>(out);
  gemm_kernel<<<P, THREADS, 0, stream>>>(V1, V2, ws, D, KC);
  loss_kernel<<<N, 256, 0, stream>>>(ws, out, P, 1.0f / (float)D);
}

// Round 13
// 132.915 us; speedup vs baseline: 1.4068x; 1.1213x over previous
//
#include <hip/hip_runtime.h>

#define BK 32          // fp32 k-elements per pipeline stage (128 B per row-visit)
#define NCHUNK 256     // grid = K-chunks; KC = D/NCHUNK = 1024
#define THREADS 1024

typedef float f32x4 __attribute__((ext_vector_type(4)));
typedef short s16x8 __attribute__((ext_vector_type(8)));

// HW packed fp32->bf16 RTNE (2 elems/instr); no builtin on gfx950 -> asm.
// Numerically validated in R11 (passed, absmax 0.0).
__device__ __forceinline__ unsigned cvtpk(float lo, float hi) {
  unsigned r;
  asm("v_cvt_pk_bf16_f32 %0, %1, %2" : "=v"(r) : "v"(lo), "v"(hi));
  return r;
}

__device__ __forceinline__ s16x8 cvt8(f32x4 a, f32x4 b) {
  union { unsigned u[4]; s16x8 v; } r;
  r.u[0] = cvtpk(a[0], a[1]);   // packs lo->bits[15:0] -> shorts [a0,a1]
  r.u[1] = cvtpk(a[2], a[3]);
  r.u[2] = cvtpk(b[0], b[1]);
  r.u[3] = cvtpk(b[2], b[3]);
  return r.v;
}

__global__ void __launch_bounds__(64) zero_kernel(float* out) {
  if (threadIdx.x == 0) out[0] = 0.f;
}

// R13 = R12 (best, 149.0 us) + v_cvt_pk_bf16_f32 on the LDS->frag path
// (VALU cut ~10x: f2bf bit-twiddle was ~4 ops/elem = 23% VALUBusy) +
// 4-way-parallel loss kernel. GEMM structure unchanged:
// split-K, block b owns chunk [b*KC,(b+1)*KC), full 256x256 fp16 partial;
// fp32 LDS ring-2 (128 KiB), global_load_lds DMA, counted vmcnt(4),
// per-block k-phase rotation (R12: +4%, anti channel-camping).
__global__ void __launch_bounds__(THREADS, 4)
gemm_kernel(const float* __restrict__ V1, const float* __restrict__ V2,
            _Float16* __restrict__ ws, int D, int KC) {
  __shared__ __align__(16) float lds[2 * 2 * 256 * BK];  // 128 KiB

  const int tid  = threadIdx.x;
  const int lane = tid & 63;
  const int wid  = tid >> 6;    // 0..15
  const int wm   = wid >> 2;    // 0..3 (M)
  const int wn   = wid & 3;     // 0..3 (N)
  const int lr   = lane & 15;
  const int lg   = lane >> 4;
  const int ns   = KC / BK;     // 32 (power of 2)
  const int nsm  = ns - 1;
  const int s0   = blockIdx.x & nsm;   // per-block k-phase rotation

  // loader role: wave covers a 32-row panel of one matrix; 4 instrs x 8 rows.
  const int mat   = wid >> 3;         // 0: V1, 1: V2
  const int panel = (wid & 7) * 32;
  const int lrow8 = lane >> 3;        // row within an 8-row group
  const int lseg  = lane & 7;         // 16B segment
  const int swz   = (lseg * 4) ^ (lrow8 << 2);   // pre-swizzled source offset

  const float* srcM = mat ? V2 : V1;
  const size_t chunk = (size_t)blockIdx.x * (size_t)KC;
  const float* gsrc[4];
#pragma unroll
  for (int i = 0; i < 4; ++i)
    gsrc[i] = srcM + (size_t)(panel + i * 8 + lrow8) * (size_t)D + chunk + swz;

  auto issue = [&](int t, int s) {
    const int tr = (t + s0) & nsm;     // rotated k-window
#pragma unroll
    for (int i = 0; i < 4; ++i) {
      const float* g = gsrc[i] + (size_t)tr * BK;
      float* l = &lds[(((s * 2 + mat) * 256) + panel + i * 8) * BK];  // wave-uniform
      __builtin_amdgcn_global_load_lds(
          (const __attribute__((address_space(1))) void*)g,
          (__attribute__((address_space(3))) void*)l, 16, 0, 0);
    }
  };

  f32x4 acc[4][4];
#pragma unroll
  for (int a = 0; a < 4; ++a)
#pragma unroll
    for (int b = 0; b < 4; ++b) acc[a][b] = f32x4{0.f, 0.f, 0.f, 0.f};

  issue(0, 0);
  issue(1, 1);     // ns >= 2 always

  for (int t = 0; t < ns; ++t) {
    const int s = t & 1;

    // stage t complete: my 4 oldest loads done (4 newer stay in flight).
    if (t + 1 < ns) asm volatile("s_waitcnt vmcnt(4)" ::: "memory");
    else            asm volatile("s_waitcnt vmcnt(0)" ::: "memory");
    __builtin_amdgcn_s_barrier();
    __builtin_amdgcn_sched_barrier(0);

    // B fragments (4x): swizzled f32x4 pair, cvt_pk to bf16
    s16x8 bf[4];
#pragma unroll
    for (int nf = 0; nf < 4; ++nf) {
      int r = wn * 64 + nf * 16 + lr;
      int base = ((s * 2 + 1) * 256 + r) * BK;
      int x = ((r & 7) << 2);
      f32x4 lo = *(const f32x4*)&lds[base + ((lg * 8 + 0) ^ x)];
      f32x4 hi = *(const f32x4*)&lds[base + ((lg * 8 + 4) ^ x)];
      bf[nf] = cvt8(lo, hi);
    }
    // A fragments streamed; MFMA overlaps next frag's ds_read
#pragma unroll
    for (int mf = 0; mf < 4; ++mf) {
      int r = wm * 64 + mf * 16 + lr;
      int base = ((s * 2 + 0) * 256 + r) * BK;
      int x = ((r & 7) << 2);
      f32x4 lo = *(const f32x4*)&lds[base + ((lg * 8 + 0) ^ x)];
      f32x4 hi = *(const f32x4*)&lds[base + ((lg * 8 + 4) ^ x)];
      s16x8 af = cvt8(lo, hi);
#pragma unroll
      for (int nf = 0; nf < 4; ++nf)
        acc[mf][nf] = __builtin_amdgcn_mfma_f32_16x16x32_bf16(af, bf[nf], acc[mf][nf], 0, 0, 0);
    }

    // all waves done READING stage s -> safe to overwrite with stage t+2
    asm volatile("s_waitcnt lgkmcnt(0)" ::: "memory");
    __builtin_amdgcn_s_barrier();
    __builtin_amdgcn_sched_barrier(0);
    if (t + 2 < ns) issue(t + 2, s);
  }

  // C/D layout: col = lane&15, row = (lane>>4)*4 + reg. fp16 partials
  // (|partial| <~ 6*sqrt(1024) ~ 200 << 65504; zmean err ~1e-6 — R5-R12 proven).
  _Float16* Cp = ws + (size_t)blockIdx.x * (256 * 256);
#pragma unroll
  for (int mf = 0; mf < 4; ++mf) {
    int i0 = wm * 64 + mf * 16 + lg * 4;
#pragma unroll
    for (int nf = 0; nf < 4; ++nf) {
      int j = wn * 64 + nf * 16 + lr;
#pragma unroll
      for (int v = 0; v < 4; ++v)
        Cp[(size_t)(i0 + v) * 256 + j] = (_Float16)acc[mf][nf][v];
    }
  }
}

// Sum P fp16 partials (4-way split across thread groups), z = dot/D,
// BCE vs identity labels: diag softplus(z)-z ; off-diag softplus(z).
__global__ void __launch_bounds__(1024)
loss_kernel(const _Float16* __restrict__ ws, float* __restrict__ out, int P, float invD) {
  const int i  = blockIdx.x;
  const int j  = threadIdx.x & 255;
  const int g4 = threadIdx.x >> 8;        // 0..3
  const int pc = P >> 2;                  // partials per group (P is a pow2 >= 4)

  const _Float16* base = ws + (size_t)(g4 * pc) * 65536 + i * 256 + j;
  float s = 0.f;
#pragma unroll 8
  for (int p = 0; p < pc; ++p) s += (float)base[(size_t)p * 65536];

  __shared__ float sred[4 * 256];
  sred[g4 * 256 + j] = s;
  __syncthreads();

  __shared__ float red[256];
  if (threadIdx.x < 256) {
    float z = (sred[j] + sred[256 + j] + sred[512 + j] + sred[768 + j]) * invD;
    red[j] = log1pf(expf(z)) - (i == j ? z : 0.f);
  }
  __syncthreads();
  for (int st = 128; st > 0; st >>= 1) {
    if (threadIdx.x < st) red[threadIdx.x] += red[threadIdx.x + st];
    __syncthreads();
  }
  if (threadIdx.x == 0) atomicAdd(out, red[0] * (1.f / 65536.f));
}

extern "C" void kernel_launch(void* const* d_in, const int* in_sizes, int n_in,
                              void* d_out, int out_size, void* d_ws, size_t ws_size,
                              hipStream_t stream) {
  const float* V1 = (const float*)d_in[0];
  const float* V2 = (const float*)d_in[1];
  float* out = (float*)d_out;
  _Float16* ws = (_Float16*)d_ws;

  const int N = 256;
  const int D = in_sizes[0] / N;   // 262144

  int P = NCHUNK;                  // 256 fp16 partials = 32 MB
  while (P > 4 && (size_t)P * 65536 * sizeof(_Float16) > ws_size) P >>= 1;
  const int KC = D / P;            // 1024

  zero_kernel<<<1, 64, 0, stream>>>(out);
  gemm_kernel<<<P, THREADS, 0, stream>>>(V1, V2, ws, D, KC);
  loss_kernel<<<N, 1024, 0, stream>>>(ws, out, P, 1.0f / (float)D);
}